// Round 4
// baseline (493.569 us; speedup 1.0000x reference)
//
#include <hip/hip_runtime.h>
#include <cstdint>

typedef unsigned short u16;
using bf16x8 = __attribute__((ext_vector_type(8))) __bf16;
using f32x4  = __attribute__((ext_vector_type(4))) float;

#define T_TOK 16384   // B * N_OBJ
#define E_NUM 8

__device__ __forceinline__ u16 f2bf(float f) {
    union { float f; unsigned u; } v; v.f = f;
    unsigned r = (v.u + 0x7FFFu + ((v.u >> 16) & 1u)) >> 16;
    return (u16)r;
}

__device__ __forceinline__ void gload_lds16(const void* g, void* l) {
    __builtin_amdgcn_global_load_lds(
        (const __attribute__((address_space(1))) void*)g,
        (__attribute__((address_space(3))) void*)l, 16, 0, 0);
}

// ---------------- prep: W (E,1024,1024) f32 -> WT (E,1024,1024) bf16 transposed ----------------
__global__ __launch_bounds__(256) void k_transpose(const float* __restrict__ W, u16* __restrict__ WT) {
    __shared__ float tile[32][33];
    int e = blockIdx.z;
    int d0 = blockIdx.x << 5, h0 = blockIdx.y << 5;
    int tx = threadIdx.x & 31, ty = threadIdx.x >> 5;   // 32x8
    const size_t eo = (size_t)e << 20;
#pragma unroll
    for (int i = 0; i < 4; ++i) {
        int r = ty + i * 8;
        tile[r][tx] = W[eo + (size_t)(d0 + r) * 1024 + h0 + tx];
    }
    __syncthreads();
#pragma unroll
    for (int i = 0; i < 4; ++i) {
        int r = ty + i * 8;
        WT[eo + (size_t)(h0 + r) * 1024 + d0 + tx] = f2bf(tile[tx][r]);
    }
}

// ---------------- router: exact fp32 logits, top-2; writes per-token info; folds x->bf16 ----------------
__global__ __launch_bounds__(256) void k_router(const float* __restrict__ x, const float* __restrict__ Wr,
                                                const float* __restrict__ br,
                                                int* __restrict__ tinfo, float* __restrict__ c1arr,
                                                u16* __restrict__ xbf) {
    const int wave = threadIdx.x >> 6, lane = threadIdx.x & 63;
    const int t = (blockIdx.x << 2) + wave;
    const float* xr = x + (size_t)t * 1024;
    u16* xbr = xbf + (size_t)t * 1024;
    float acc[8] = {0, 0, 0, 0, 0, 0, 0, 0};
#pragma unroll
    for (int i = 0; i < 16; ++i) {
        int d = (i << 6) + lane;
        float xv = xr[d];
        xbr[d] = f2bf(xv);
        float4 w0 = *(const float4*)(Wr + d * 8);
        float4 w1 = *(const float4*)(Wr + d * 8 + 4);
        acc[0] += xv * w0.x; acc[1] += xv * w0.y; acc[2] += xv * w0.z; acc[3] += xv * w0.w;
        acc[4] += xv * w1.x; acc[5] += xv * w1.y; acc[6] += xv * w1.z; acc[7] += xv * w1.w;
    }
#pragma unroll
    for (int off = 32; off > 0; off >>= 1)
#pragma unroll
        for (int e = 0; e < 8; ++e) acc[e] += __shfl_xor(acc[e], off);

    if (lane == 0) {
        float v1 = -1e30f, v2 = -1e30f; int i1 = 0, i2 = 0;
#pragma unroll
        for (int e = 0; e < 8; ++e) {
            float v = acc[e] + br[e];
            if (v > v1) { v2 = v1; i2 = i1; v1 = v; i1 = e; }
            else if (v > v2) { v2 = v; i2 = e; }
        }
        float c1 = 1.f / (1.f + expf(v2 - v1));
        tinfo[t] = i1 | (i2 << 4);
        c1arr[t] = c1;
    }
}

// ---------------- scatter: LDS histogram -> per-block base -> 8 per-expert lists ----------------
__global__ __launch_bounds__(1024) void k_scatter(const int* __restrict__ tinfo, const float* __restrict__ c1arr,
                                                  int* __restrict__ cnt, int* __restrict__ tok,
                                                  float* __restrict__ coef) {
    __shared__ int lcnt[8];
    __shared__ int lbase[8];
    const int tid = threadIdx.x;
    const int t = blockIdx.x * 1024 + tid;
    if (tid < 8) lcnt[tid] = 0;
    __syncthreads();
    int info = tinfo[t];
    float c1 = c1arr[t];
    int g1 = info & 15;
    int g2 = (info >> 4) & 15;
    int o1 = atomicAdd(&lcnt[g1], 1);
    int o2 = atomicAdd(&lcnt[g2], 1);
    __syncthreads();
    if (tid < 8) lbase[tid] = atomicAdd(cnt + tid, lcnt[tid]);
    __syncthreads();
    int p1 = lbase[g1] + o1;
    tok[(g1 << 14) + p1] = t; coef[(g1 << 14) + p1] = c1;
    int p2 = lbase[g2] + o2;
    tok[(g2 << 14) + p2] = t; coef[(g2 << 14) + p2] = 1.f - c1;
}

// ---------------- grouped GEMM, 256x256, BK=64, counted-vmcnt 4-phase pipeline (T3+T4+T5) ----------------
// 8 waves (2M x 4N), per-wave C = 128x64 = acc[8][4]. A/B split into 2 half-tiles of
// 128x64 (16 KB), double-buffered -> 128 KB LDS. Per K-tile t (buf p=t&1), 4 phases;
// each phase: {stage one half-tile of t+1 into buf p^1 (2 gload_lds) | ds_read quadrant
// -> s_barrier -> lgkmcnt(0)+sched_barrier -> setprio(1) 16 MFMA setprio(0) -> s_barrier}.
// vmcnt(2) ONCE per K-tile (phase 0, after issuing next A-half): all 8 staging loads of
// tile t have landed, just-issued 2 stay in flight (T4: never drain to 0 in the loop).
// Stage order A,A,B,B: A (HBM-latency token gather) gets 3-4 phases of cover; B (L2-warm
// weight panel) needs ~1. Safety: all reads of buf p^1 end before q3(t-1)'s final
// barrier; every stage into p^1 is issued after it. Raw s_barrier throughout - no
// compiler vmcnt(0) drains inside the K-loop.
// PHASE 0: h = relu(gather(xbf) @ W1T + b1) -> hbuf (bf16)
// PHASE 1: out[tok] += coef * (hbuf @ W2T + b2)   (atomicAdd, out pre-zeroed)
template <int PHASE>
__global__ __launch_bounds__(512, 2) void k_gemm(
    const int* __restrict__ cnt, const int* __restrict__ tok, const float* __restrict__ coef,
    const u16* __restrict__ xbf, const u16* __restrict__ w1t, const u16* __restrict__ w2t,
    const float* __restrict__ b1, const float* __restrict__ b2,
    u16* __restrict__ hbuf, float* __restrict__ out)
{
    __shared__ u16 As[2][2][128 * 64];   // [buf][half] 64 KB
    __shared__ u16 Bs[2][2][128 * 64];   // 64 KB
    __shared__ int s_cnt[8];
    __shared__ int tok_s[256];
    __shared__ float coef_s[256];

    const int tid = threadIdx.x;
    if (tid < 8) s_cnt[tid] = cnt[tid];
    __syncthreads();

    // XCD-aware remap (bijective: 544 = 8*68)
    int bid = blockIdx.x + blockIdx.y * 68;
    int lin = (bid & 7) * 68 + (bid >> 3);
    int xt = lin >> 2, yt = lin & 3;

    // uniform scan: which (group, tile) is this block?
    int g = -1, tile = 0, r0 = 0, mt = xt, rb = 0;
    for (int gg = 0; gg < 8; ++gg) {
        int c = s_cnt[gg], tg = (c + 255) >> 8;
        if (g < 0) {
            if (mt < tg) { g = gg; tile = mt; r0 = rb + (mt << 8); }
            else mt -= tg;
        }
        rb += c;
    }
    if (g < 0) return;
    const int cntg = s_cnt[g];
    const int e = g;
    const int nb = yt << 8;
    const int rowlim = cntg - (tile << 8);

    if (tid < 256) {
        int idx = (tile << 8) + tid;
        bool valid = idx < cntg;
        tok_s[tid] = valid ? tok[(g << 14) + idx] : 0;
        coef_s[tid] = valid ? coef[(g << 14) + idx] : 0.f;
    }
    __syncthreads();   // full drain; vmcnt==0 entering the pipeline

    const int w = tid >> 6, l = tid & 63;       // 8 waves
    const int wm = w >> 2, wn = w & 3;          // 2M x 4N
    const int wh = wn >> 1, wnl = wn & 1;       // B-half, col-block within half
    const int l15 = l & 15;
    const u16* asrc = (PHASE == 0) ? xbf : hbuf;
    const u16* bsrc = (PHASE == 0) ? w1t : w2t;

    // T2 swizzle: LDS linear for gload_lds; global SOURCE col pre-XORed; reads XOR back.
    const int sw = ((l & 7) ^ (l >> 3)) << 3;
    const int xk = (l & 7) << 3;
    const int co0 = (((l >> 4) << 3)) ^ xk;          // k-offset 0  within BK=64
    const int co1 = (32 + ((l >> 4) << 3)) ^ xk;     // k-offset 32

    // staging: s = half*2 + j; row_in_tile = half*128 + j*64 + w*8 + (l>>3)
    const u16* aptr[4]; const u16* bptr[4]; int ldso[4];
#pragma unroll
    for (int s = 0; s < 4; ++s) {
        int half = s >> 1, j = s & 1;
        int row = half * 128 + j * 64 + (w << 3) + (l >> 3);
        int arow = (PHASE == 0) ? tok_s[row] : (r0 + row);
        aptr[s] = asrc + ((size_t)arow << 10) + sw;
        bptr[s] = bsrc + ((size_t)((e << 10) + nb + row)) * 1024 + sw;
        ldso[s] = (j * 64 + (w << 3)) * 64;   // elem offset within a 128x64 half-slot
    }

    f32x4 acc[8][4];
#pragma unroll
    for (int mi = 0; mi < 8; ++mi)
#pragma unroll
        for (int ni = 0; ni < 4; ++ni) { acc[mi][ni][0] = 0.f; acc[mi][ni][1] = 0.f; acc[mi][ni][2] = 0.f; acc[mi][ni][3] = 0.f; }

    bf16x8 bfr[4][2];   // B frags: read once per K-tile (phase 0), reused in all 4 phases
    bf16x8 af[2][2];    // A frags for the current quadrant

#define STG_A(BUF, HALF, KO) \
    gload_lds16(aptr[(HALF)*2+0] + (KO), &As[BUF][HALF][ldso[(HALF)*2+0]]); \
    gload_lds16(aptr[(HALF)*2+1] + (KO), &As[BUF][HALF][ldso[(HALF)*2+1]]);
#define STG_B(BUF, HALF, KO) \
    gload_lds16(bptr[(HALF)*2+0] + (KO), &Bs[BUF][HALF][ldso[(HALF)*2+0]]); \
    gload_lds16(bptr[(HALF)*2+1] + (KO), &Bs[BUF][HALF][ldso[(HALF)*2+1]]);

#define LOAD_B(P) { \
    _Pragma("unroll") for (int ni = 0; ni < 4; ++ni) { \
        bfr[ni][0] = *(const bf16x8*)&Bs[P][wh][(wnl*64 + ni*16 + l15)*64 + co0]; \
        bfr[ni][1] = *(const bf16x8*)&Bs[P][wh][(wnl*64 + ni*16 + l15)*64 + co1]; } }
#define LOAD_A(P, Q) { \
    _Pragma("unroll") for (int i = 0; i < 2; ++i) { \
        af[i][0] = *(const bf16x8*)&As[P][wm][(((Q)*2+i)*16 + l15)*64 + co0]; \
        af[i][1] = *(const bf16x8*)&As[P][wm][(((Q)*2+i)*16 + l15)*64 + co1]; } }
#define MFMA_Q(Q) { \
    _Pragma("unroll") for (int i = 0; i < 2; ++i) \
    _Pragma("unroll") for (int ni = 0; ni < 4; ++ni) { \
        acc[(Q)*2+i][ni] = __builtin_amdgcn_mfma_f32_16x16x32_bf16(af[i][0], bfr[ni][0], acc[(Q)*2+i][ni], 0, 0, 0); \
        acc[(Q)*2+i][ni] = __builtin_amdgcn_mfma_f32_16x16x32_bf16(af[i][1], bfr[ni][1], acc[(Q)*2+i][ni], 0, 0, 0); } }

// phase 0: stage next A-half0, counted vmcnt, barrier, read B(all)+A(q0), MFMA q0
#define PH0(P, PN, KO) \
    STG_A(PN, 0, KO); \
    asm volatile("s_waitcnt vmcnt(2)" ::: "memory"); \
    __builtin_amdgcn_s_barrier(); \
    LOAD_B(P); \
    LOAD_A(P, 0); \
    asm volatile("s_waitcnt lgkmcnt(0)" ::: "memory"); \
    __builtin_amdgcn_sched_barrier(0); \
    __builtin_amdgcn_s_setprio(1); \
    MFMA_Q(0); \
    __builtin_amdgcn_s_setprio(0); \
    __builtin_amdgcn_s_barrier();
// phases 1-3: stage + ds_read before barrier (reads overlap the barrier wait)
#define PHN(P, Q, STGOP) \
    STGOP \
    LOAD_A(P, Q); \
    __builtin_amdgcn_s_barrier(); \
    asm volatile("s_waitcnt lgkmcnt(0)" ::: "memory"); \
    __builtin_amdgcn_sched_barrier(0); \
    __builtin_amdgcn_s_setprio(1); \
    MFMA_Q(Q); \
    __builtin_amdgcn_s_setprio(0); \
    __builtin_amdgcn_s_barrier();

#define TILE(P, PN, KO) \
    PH0(P, PN, KO) \
    PHN(P, 1, STG_A(PN, 1, KO)) \
    PHN(P, 2, STG_B(PN, 0, KO)) \
    PHN(P, 3, STG_B(PN, 1, KO))

    // prologue: stage tile 0 into buf0 (8 loads; vmcnt(2) in first PH0 waits for them)
    STG_A(0, 0, 0); STG_A(0, 1, 0); STG_B(0, 0, 0); STG_B(0, 1, 0);

    for (int kc = 0; kc < 16; kc += 2) {
        const int ko1 = (kc + 1) << 6;
        const int ko2 = (kc + 2) << 6;   // kc=14 -> 1024: junk stage into dead buf, in-bounds reads
        TILE(0, 1, ko1)
        TILE(1, 0, ko2)
    }

#undef STG_A
#undef STG_B
#undef LOAD_B
#undef LOAD_A
#undef MFMA_Q
#undef PH0
#undef PHN
#undef TILE

    const int rq = (l >> 4) << 2;
#pragma unroll
    for (int ni = 0; ni < 4; ++ni) {
        int ccol = (wn << 6) + (ni << 4) + l15;
        float bias = (PHASE == 0 ? b1 : b2)[((size_t)e << 10) + nb + ccol];
#pragma unroll
        for (int mi = 0; mi < 8; ++mi) {
            int rbase = (wm << 7) + (mi << 4) + rq;
#pragma unroll
            for (int j = 0; j < 4; ++j) {
                int r = rbase + j;
                if (r < rowlim) {
                    float v = acc[mi][ni][j] + bias;
                    if constexpr (PHASE == 0) {
                        v = fmaxf(v, 0.f);
                        hbuf[(size_t)(r0 + r) * 1024 + nb + ccol] = f2bf(v);
                    } else {
                        atomicAdd(out + ((size_t)tok_s[r] << 10) + nb + ccol, v * coef_s[r]);
                    }
                }
            }
        }
    }
}

// ---------------- insurance fallback (ws too small): slow but correct ----------------
__global__ __launch_bounds__(256) void k_naive(const float* __restrict__ x, const float* __restrict__ Wr,
    const float* __restrict__ br, const float* __restrict__ W1, const float* __restrict__ b1,
    const float* __restrict__ W2, const float* __restrict__ b2, float* __restrict__ out)
{
    __shared__ float xs[1024];
    __shared__ float hs[1024];
    __shared__ float red[4];
    __shared__ float lg[8];
    const int tid = threadIdx.x;
    const size_t t = blockIdx.x;
    for (int i = tid; i < 1024; i += 256) xs[i] = x[t * 1024 + i];
    __syncthreads();
    float lacc[8] = {0, 0, 0, 0, 0, 0, 0, 0};
    for (int d = tid; d < 1024; d += 256) {
        float xv = xs[d];
#pragma unroll
        for (int e = 0; e < 8; ++e) lacc[e] += xv * Wr[d * 8 + e];
    }
    for (int e = 0; e < 8; ++e) {
        float v = lacc[e];
        for (int off = 32; off > 0; off >>= 1) v += __shfl_xor(v, off);
        if ((tid & 63) == 0) red[tid >> 6] = v;
        __syncthreads();
        if (tid == 0) lg[e] = red[0] + red[1] + red[2] + red[3] + br[e];
        __syncthreads();
    }
    float v1 = -1e30f, v2 = -1e30f; int i1 = 0, i2 = 0;
    for (int e = 0; e < 8; ++e) {
        float v = lg[e];
        if (v > v1) { v2 = v1; i2 = i1; v1 = v; i1 = e; }
        else if (v > v2) { v2 = v; i2 = e; }
    }
    float c1 = 1.f / (1.f + expf(v2 - v1)), c2 = 1.f - c1;
    float yacc[4] = {0, 0, 0, 0};
    for (int slot = 0; slot < 2; ++slot) {
        int e = slot ? i2 : i1;
        float cw = slot ? c2 : c1;
        __syncthreads();
        float ha[4];
        for (int jb = 0; jb < 4; ++jb) {
            int j = (jb << 8) + tid;
            float a = b1[(e << 10) + j];
            for (int d = 0; d < 1024; ++d) a += xs[d] * W1[(((size_t)e << 10) + d) * 1024 + j];
            ha[jb] = fmaxf(a, 0.f);
        }
        for (int jb = 0; jb < 4; ++jb) hs[(jb << 8) + tid] = ha[jb];
        __syncthreads();
        for (int ob = 0; ob < 4; ++ob) {
            int o = (ob << 8) + tid;
            float a = b2[(e << 10) + o];
            for (int h = 0; h < 1024; ++h) a += hs[h] * W2[(((size_t)e << 10) + h) * 1024 + o];
            yacc[ob] += cw * a;
        }
    }
    for (int ob = 0; ob < 4; ++ob) out[t * 1024 + (ob << 8) + tid] = yacc[ob];
}

extern "C" void kernel_launch(void* const* d_in, const int* in_sizes, int n_in,
                              void* d_out, int out_size, void* d_ws, size_t ws_size,
                              hipStream_t stream) {
    const float* x  = (const float*)d_in[0];
    const float* Wr = (const float*)d_in[1];
    const float* br = (const float*)d_in[2];
    const float* W1 = (const float*)d_in[3];
    const float* b1 = (const float*)d_in[4];
    const float* W2 = (const float*)d_in[5];
    const float* b2 = (const float*)d_in[6];
    float* out = (float*)d_out;

    const size_t OFF_TOK   = (size_t)1 << 20;
    const size_t OFF_COEF  = (size_t)2 << 20;
    const size_t OFF_TINFO = (size_t)3 << 20;
    const size_t OFF_C1    = OFF_TINFO + (size_t)T_TOK * 4;
    const size_t OFF_XBF   = (size_t)4 << 20;
    const size_t OFF_W1T   = OFF_XBF + (size_t)T_TOK * 1024 * 2;          // +32MB
    const size_t OFF_W2T   = OFF_W1T + (size_t)E_NUM * 1024 * 1024 * 2;   // +16MB
    const size_t OFF_H     = OFF_W2T + (size_t)E_NUM * 1024 * 1024 * 2;   // +16MB
    const size_t WS_NEED   = OFF_H + (size_t)(2 * T_TOK + 1536) * 1024 * 2; // h + ragged/OOB pad

    if (ws_size < WS_NEED) {
        k_naive<<<T_TOK, 256, 0, stream>>>(x, Wr, br, W1, b1, W2, b2, out);
        return;
    }

    char* ws = (char*)d_ws;
    int*   cnt   = (int*)ws;
    int*   tok   = (int*)(ws + OFF_TOK);
    float* coef  = (float*)(ws + OFF_COEF);
    int*   tinfo = (int*)(ws + OFF_TINFO);
    float* c1arr = (float*)(ws + OFF_C1);
    u16*   xbf   = (u16*)(ws + OFF_XBF);
    u16*   w1t   = (u16*)(ws + OFF_W1T);
    u16*   w2t   = (u16*)(ws + OFF_W2T);
    u16*   hbuf  = (u16*)(ws + OFF_H);

    hipMemsetAsync(cnt, 0, 64, stream);
    hipMemsetAsync(d_out, 0, (size_t)out_size * sizeof(float), stream);
    k_transpose<<<dim3(32, 32, 8), 256, 0, stream>>>(W1, w1t);
    k_transpose<<<dim3(32, 32, 8), 256, 0, stream>>>(W2, w2t);
    k_router<<<4096, 256, 0, stream>>>(x, Wr, br, tinfo, c1arr, xbf);
    k_scatter<<<16, 1024, 0, stream>>>(tinfo, c1arr, cnt, tok, coef);
    dim3 gg(68, 8);
    k_gemm<0><<<gg, 512, 0, stream>>>(cnt, tok, coef, xbf, w1t, w2t, b1, b2, hbuf, out);
    k_gemm<1><<<gg, 512, 0, stream>>>(cnt, tok, coef, xbf, w1t, w2t, b1, b2, hbuf, out);
}

// Round 5
// 393.137 us; speedup vs baseline: 1.2555x; 1.2555x over previous
//
#include <hip/hip_runtime.h>
#include <cstdint>

typedef unsigned short u16;
using bf16x8 = __attribute__((ext_vector_type(8))) __bf16;
using f32x4  = __attribute__((ext_vector_type(4))) float;

#define T_TOK 16384   // B * N_OBJ
#define E_NUM 8

__device__ __forceinline__ u16 f2bf(float f) {
    union { float f; unsigned u; } v; v.f = f;
    unsigned r = (v.u + 0x7FFFu + ((v.u >> 16) & 1u)) >> 16;
    return (u16)r;
}

__device__ __forceinline__ void gload_lds16(const void* g, void* l) {
    __builtin_amdgcn_global_load_lds(
        (const __attribute__((address_space(1))) void*)g,
        (__attribute__((address_space(3))) void*)l, 16, 0, 0);
}

// ---------------- prep: W (E,1024,1024) f32 -> WT (E,1024,1024) bf16 transposed ----------------
__global__ __launch_bounds__(256) void k_transpose(const float* __restrict__ W, u16* __restrict__ WT) {
    __shared__ float tile[32][33];
    int e = blockIdx.z;
    int d0 = blockIdx.x << 5, h0 = blockIdx.y << 5;
    int tx = threadIdx.x & 31, ty = threadIdx.x >> 5;   // 32x8
    const size_t eo = (size_t)e << 20;
#pragma unroll
    for (int i = 0; i < 4; ++i) {
        int r = ty + i * 8;
        tile[r][tx] = W[eo + (size_t)(d0 + r) * 1024 + h0 + tx];
    }
    __syncthreads();
#pragma unroll
    for (int i = 0; i < 4; ++i) {
        int r = ty + i * 8;
        WT[eo + (size_t)(h0 + r) * 1024 + d0 + tx] = f2bf(tile[tx][r]);
    }
}

// ---------------- router: exact fp32 logits, top-2; writes per-token info; folds x->bf16 ----------------
__global__ __launch_bounds__(256) void k_router(const float* __restrict__ x, const float* __restrict__ Wr,
                                                const float* __restrict__ br,
                                                int* __restrict__ tinfo, float* __restrict__ c1arr,
                                                u16* __restrict__ xbf) {
    const int wave = threadIdx.x >> 6, lane = threadIdx.x & 63;
    const int t = (blockIdx.x << 2) + wave;
    const float* xr = x + (size_t)t * 1024;
    u16* xbr = xbf + (size_t)t * 1024;
    float acc[8] = {0, 0, 0, 0, 0, 0, 0, 0};
#pragma unroll
    for (int i = 0; i < 16; ++i) {
        int d = (i << 6) + lane;
        float xv = xr[d];
        xbr[d] = f2bf(xv);
        float4 w0 = *(const float4*)(Wr + d * 8);
        float4 w1 = *(const float4*)(Wr + d * 8 + 4);
        acc[0] += xv * w0.x; acc[1] += xv * w0.y; acc[2] += xv * w0.z; acc[3] += xv * w0.w;
        acc[4] += xv * w1.x; acc[5] += xv * w1.y; acc[6] += xv * w1.z; acc[7] += xv * w1.w;
    }
#pragma unroll
    for (int off = 32; off > 0; off >>= 1)
#pragma unroll
        for (int e = 0; e < 8; ++e) acc[e] += __shfl_xor(acc[e], off);

    if (lane == 0) {
        float v1 = -1e30f, v2 = -1e30f; int i1 = 0, i2 = 0;
#pragma unroll
        for (int e = 0; e < 8; ++e) {
            float v = acc[e] + br[e];
            if (v > v1) { v2 = v1; i2 = i1; v1 = v; i1 = e; }
            else if (v > v2) { v2 = v; i2 = e; }
        }
        float c1 = 1.f / (1.f + expf(v2 - v1));
        tinfo[t] = i1 | (i2 << 4);
        c1arr[t] = c1;
    }
}

// ---------------- scatter: LDS histogram -> per-block base -> 8 per-expert lists ----------------
__global__ __launch_bounds__(1024) void k_scatter(const int* __restrict__ tinfo, const float* __restrict__ c1arr,
                                                  int* __restrict__ cnt, int* __restrict__ tok,
                                                  float* __restrict__ coef) {
    __shared__ int lcnt[8];
    __shared__ int lbase[8];
    const int tid = threadIdx.x;
    const int t = blockIdx.x * 1024 + tid;
    if (tid < 8) lcnt[tid] = 0;
    __syncthreads();
    int info = tinfo[t];
    float c1 = c1arr[t];
    int g1 = info & 15;
    int g2 = (info >> 4) & 15;
    int o1 = atomicAdd(&lcnt[g1], 1);
    int o2 = atomicAdd(&lcnt[g2], 1);
    __syncthreads();
    if (tid < 8) lbase[tid] = atomicAdd(cnt + tid, lcnt[tid]);
    __syncthreads();
    int p1 = lbase[g1] + o1;
    tok[(g1 << 14) + p1] = t; coef[(g1 << 14) + p1] = c1;
    int p2 = lbase[g2] + o2;
    tok[(g2 << 14) + p2] = t; coef[(g2 << 14) + p2] = 1.f - c1;
}

// ---------------- grouped GEMM, 128x64 tile, BK=64, ping-pong dbuf + counted vmcnt AT occupancy ----------------
// The untested combination: 1-deep prefetch pipeline AND 12 waves/CU.
// Static buffers a0/b0/a1/b1 (no dynamic indexing). Per K-step: release-barrier ->
// STAGE next tile into freed buffer (6 gload_lds, stay in flight) -> vmcnt(6) waits
// ONLY for the other buffer's 6 loads -> arrival-barrier -> COMPUTE (12 ds_read_b128 +
// 16 MFMA/wave) covers the in-flight loads. lgkmcnt(0) before each release barrier
// guarantees all reads of the freed buffer completed (no restage race). No vmcnt(0)
// anywhere in the main loop (T4); peeled tail keeps all vmcnt literals.
// 4 waves, per-wave 64x32 output (acc[4][2]); LDS 48KB+1.2KB -> 3 blocks/CU.
// PHASE 0: h = relu(gather(xbf) @ W1T + b1) -> hbuf (bf16)
// PHASE 1: out[tok] += coef * (hbuf @ W2T + b2)   (atomicAdd, out pre-zeroed)
template <int PHASE>
__global__ __launch_bounds__(256, 3) void k_gemm(
    const int* __restrict__ cnt, const int* __restrict__ tok, const float* __restrict__ coef,
    const u16* __restrict__ xbf, const u16* __restrict__ w1t, const u16* __restrict__ w2t,
    const float* __restrict__ b1, const float* __restrict__ b2,
    u16* __restrict__ hbuf, float* __restrict__ out)
{
    __shared__ u16 a0_s[128 * 64];   // 16 KB
    __shared__ u16 a1_s[128 * 64];   // 16 KB
    __shared__ u16 b0_s[64 * 64];    //  8 KB
    __shared__ u16 b1_s[64 * 64];    //  8 KB
    __shared__ int s_cnt[8];
    __shared__ int tok_s[128];
    __shared__ float coef_s[128];

    const int tid = threadIdx.x;
    if (tid < 8) s_cnt[tid] = cnt[tid];
    __syncthreads();

    // XCD-aware remap (bijective: 4352 = 8*544): each XCD owns 544 consecutive
    // linear tiles; each row-tile sweeps all 16 col-tiles -> A-slice L2 reuse.
    int bid = blockIdx.x + blockIdx.y * 272;            // hw flat id, 4352 total
    int lin = (bid & 7) * 544 + (bid >> 3);
    int xt = lin >> 4, yt = lin & 15;

    // uniform scan: which (group, tile) is this block?
    int g = -1, tile = 0, r0 = 0, mt = xt, rb = 0;
    for (int gg = 0; gg < 8; ++gg) {
        int c = s_cnt[gg], tg = (c + 127) >> 7;
        if (g < 0) {
            if (mt < tg) { g = gg; tile = mt; r0 = rb + (mt << 7); }
            else mt -= tg;
        }
        rb += c;
    }
    if (g < 0) return;
    const int cntg = s_cnt[g];
    const int e = g;
    const int nb = yt << 6;
    const int rowlim = cntg - (tile << 7);

    if (tid < 128) {
        int idx = (tile << 7) + tid;
        bool valid = idx < cntg;
        tok_s[tid] = valid ? tok[(g << 14) + idx] : 0;
        coef_s[tid] = valid ? coef[(g << 14) + idx] : 0.f;
    }
    __syncthreads();   // vmcnt==0 entering the pipeline

    const int w = tid >> 6, l = tid & 63;
    const int wrow = (w >> 1) << 6, wcol = (w & 1) << 5;
    const u16* asrc = (PHASE == 0) ? xbf : hbuf;
    const u16* bsrc = (PHASE == 0) ? w1t : w2t;
    const size_t brow0 = ((size_t)e << 10) + nb;

    // T2 swizzle: LDS stays linear for global_load_lds; global SOURCE column is
    // pre-XORed so a swizzled ds_read returns the unswizzled element.
    const int sw = ((l & 7) ^ (l >> 3)) << 3;   // staging source col offset (elements)
    const int xk = (l & 7) << 3;                // read col XOR key (frag row&7 == l&7)

    // staging: A = 4 slots x 32 rows, B = 2 slots x 32 rows; 6 gload_lds / thread / tile
    const u16* aptr[4]; int ldsa[4];
#pragma unroll
    for (int j = 0; j < 4; ++j) {
        int row = (j << 5) + (w << 3) + (l >> 3);
        int arow = (PHASE == 0) ? tok_s[row] : (r0 + row);
        aptr[j] = asrc + ((size_t)arow << 10) + sw;
        ldsa[j] = ((j << 5) + (w << 3)) * 64;
    }
    const u16* bptr[2]; int ldsb[2];
#pragma unroll
    for (int j = 0; j < 2; ++j) {
        int brow = (j << 5) + (w << 3) + (l >> 3);
        bptr[j] = bsrc + (brow0 + brow) * 1024 + sw;
        ldsb[j] = ((j << 5) + (w << 3)) * 64;
    }

    f32x4 acc[4][2];
#pragma unroll
    for (int mi = 0; mi < 4; ++mi)
#pragma unroll
        for (int ni = 0; ni < 2; ++ni) { acc[mi][ni][0] = 0.f; acc[mi][ni][1] = 0.f; acc[mi][ni][2] = 0.f; acc[mi][ni][3] = 0.f; }

#define STAGE(AS, BS, KO)                                                      \
    {                                                                          \
        _Pragma("unroll")                                                      \
        for (int j = 0; j < 4; ++j) gload_lds16(aptr[j] + (KO), &AS[ldsa[j]]); \
        _Pragma("unroll")                                                      \
        for (int j = 0; j < 2; ++j) gload_lds16(bptr[j] + (KO), &BS[ldsb[j]]); \
    }

#define COMPUTE(AS, BS)                                                        \
    {                                                                          \
        _Pragma("unroll")                                                      \
        for (int ks = 0; ks < 64; ks += 32) {                                  \
            const int co = (ks + ((l >> 4) << 3)) ^ xk;                        \
            bf16x8 af[4], bfr[2];                                              \
            _Pragma("unroll")                                                  \
            for (int mi = 0; mi < 4; ++mi)                                     \
                af[mi] = *(const bf16x8*)&AS[(wrow + (mi << 4) + (l & 15)) * 64 + co]; \
            _Pragma("unroll")                                                  \
            for (int ni = 0; ni < 2; ++ni)                                     \
                bfr[ni] = *(const bf16x8*)&BS[(wcol + (ni << 4) + (l & 15)) * 64 + co]; \
            _Pragma("unroll")                                                  \
            for (int mi = 0; mi < 4; ++mi)                                     \
                _Pragma("unroll")                                              \
                for (int ni = 0; ni < 2; ++ni)                                 \
                    acc[mi][ni] = __builtin_amdgcn_mfma_f32_16x16x32_bf16(af[mi], bfr[ni], acc[mi][ni], 0, 0, 0); \
        }                                                                      \
    }

#define VM6  asm volatile("s_waitcnt vmcnt(6)" ::: "memory")
#define VM0  asm volatile("s_waitcnt vmcnt(0)" ::: "memory")
#define LGK0 asm volatile("s_waitcnt lgkmcnt(0)" ::: "memory")
#define BAR() { asm volatile("" ::: "memory"); __builtin_amdgcn_s_barrier(); asm volatile("" ::: "memory"); }

    // prologue: stage tiles 0,1 (12 loads); wait tile0 only
    STAGE(a0_s, b0_s, 0);
    STAGE(a1_s, b1_s, 64);
    VM6; BAR();

    // steady state invariant at loop top: buf0 = tile kc (landed), buf1 = tile kc+1 (6 in flight)
    for (int kc = 0; kc < 12; kc += 2) {
        COMPUTE(a0_s, b0_s);                  // tile kc; covers buf1 flight
        LGK0; BAR();                          // all waves done reading buf0
        STAGE(a0_s, b0_s, (kc + 2) << 6);     // outstanding 12
        VM6; BAR();                           // buf1 (tile kc+1) landed everywhere
        COMPUTE(a1_s, b1_s);                  // tile kc+1; covers buf0 flight
        LGK0; BAR();
        STAGE(a1_s, b1_s, (kc + 3) << 6);     // outstanding 12
        VM6; BAR();                           // buf0 (tile kc+2) landed
    }
    // tail: buf0 = tile12, buf1 = tile13 in flight
    COMPUTE(a0_s, b0_s);                      // tile 12
    LGK0; BAR();
    STAGE(a0_s, b0_s, 14 << 6);
    VM6; BAR();                               // tile 13 landed
    COMPUTE(a1_s, b1_s);                      // tile 13
    LGK0; BAR();
    STAGE(a1_s, b1_s, 15 << 6);
    VM6; BAR();                               // tile 14 landed
    COMPUTE(a0_s, b0_s);                      // tile 14
    LGK0; BAR();
    VM0; BAR();                               // tile 15 landed
    COMPUTE(a1_s, b1_s);                      // tile 15

#undef STAGE
#undef COMPUTE
#undef VM6
#undef VM0
#undef LGK0
#undef BAR

    const int rq = (l >> 4) << 2;
    const int cl = l & 15;
#pragma unroll
    for (int ni = 0; ni < 2; ++ni) {
        int ccol = wcol + (ni << 4) + cl;
        float bias = (PHASE == 0 ? b1 : b2)[((size_t)e << 10) + nb + ccol];
#pragma unroll
        for (int mi = 0; mi < 4; ++mi) {
            int rbase = wrow + (mi << 4) + rq;
#pragma unroll
            for (int j = 0; j < 4; ++j) {
                int r = rbase + j;
                if (r < rowlim) {
                    float v = acc[mi][ni][j] + bias;
                    if constexpr (PHASE == 0) {
                        v = fmaxf(v, 0.f);
                        hbuf[(size_t)(r0 + r) * 1024 + nb + ccol] = f2bf(v);
                    } else {
                        atomicAdd(out + ((size_t)tok_s[r] << 10) + nb + ccol, v * coef_s[r]);
                    }
                }
            }
        }
    }
}

// ---------------- insurance fallback (ws too small): slow but correct ----------------
__global__ __launch_bounds__(256) void k_naive(const float* __restrict__ x, const float* __restrict__ Wr,
    const float* __restrict__ br, const float* __restrict__ W1, const float* __restrict__ b1,
    const float* __restrict__ W2, const float* __restrict__ b2, float* __restrict__ out)
{
    __shared__ float xs[1024];
    __shared__ float hs[1024];
    __shared__ float red[4];
    __shared__ float lg[8];
    const int tid = threadIdx.x;
    const size_t t = blockIdx.x;
    for (int i = tid; i < 1024; i += 256) xs[i] = x[t * 1024 + i];
    __syncthreads();
    float lacc[8] = {0, 0, 0, 0, 0, 0, 0, 0};
    for (int d = tid; d < 1024; d += 256) {
        float xv = xs[d];
#pragma unroll
        for (int e = 0; e < 8; ++e) lacc[e] += xv * Wr[d * 8 + e];
    }
    for (int e = 0; e < 8; ++e) {
        float v = lacc[e];
        for (int off = 32; off > 0; off >>= 1) v += __shfl_xor(v, off);
        if ((tid & 63) == 0) red[tid >> 6] = v;
        __syncthreads();
        if (tid == 0) lg[e] = red[0] + red[1] + red[2] + red[3] + br[e];
        __syncthreads();
    }
    float v1 = -1e30f, v2 = -1e30f; int i1 = 0, i2 = 0;
    for (int e = 0; e < 8; ++e) {
        float v = lg[e];
        if (v > v1) { v2 = v1; i2 = i1; v1 = v; i1 = e; }
        else if (v > v2) { v2 = v; i2 = e; }
    }
    float c1 = 1.f / (1.f + expf(v2 - v1)), c2 = 1.f - c1;
    float yacc[4] = {0, 0, 0, 0};
    for (int slot = 0; slot < 2; ++slot) {
        int e = slot ? i2 : i1;
        float cw = slot ? c2 : c1;
        __syncthreads();
        float ha[4];
        for (int jb = 0; jb < 4; ++jb) {
            int j = (jb << 8) + tid;
            float a = b1[(e << 10) + j];
            for (int d = 0; d < 1024; ++d) a += xs[d] * W1[(((size_t)e << 10) + d) * 1024 + j];
            ha[jb] = fmaxf(a, 0.f);
        }
        for (int jb = 0; jb < 4; ++jb) hs[(jb << 8) + tid] = ha[jb];
        __syncthreads();
        for (int ob = 0; ob < 4; ++ob) {
            int o = (ob << 8) + tid;
            float a = b2[(e << 10) + o];
            for (int h = 0; h < 1024; ++h) a += hs[h] * W2[(((size_t)e << 10) + h) * 1024 + o];
            yacc[ob] += cw * a;
        }
    }
    for (int ob = 0; ob < 4; ++ob) out[t * 1024 + (ob << 8) + tid] = yacc[ob];
}

extern "C" void kernel_launch(void* const* d_in, const int* in_sizes, int n_in,
                              void* d_out, int out_size, void* d_ws, size_t ws_size,
                              hipStream_t stream) {
    const float* x  = (const float*)d_in[0];
    const float* Wr = (const float*)d_in[1];
    const float* br = (const float*)d_in[2];
    const float* W1 = (const float*)d_in[3];
    const float* b1 = (const float*)d_in[4];
    const float* W2 = (const float*)d_in[5];
    const float* b2 = (const float*)d_in[6];
    float* out = (float*)d_out;

    const size_t OFF_TOK   = (size_t)1 << 20;
    const size_t OFF_COEF  = (size_t)2 << 20;
    const size_t OFF_TINFO = (size_t)3 << 20;
    const size_t OFF_C1    = OFF_TINFO + (size_t)T_TOK * 4;
    const size_t OFF_XBF   = (size_t)4 << 20;
    const size_t OFF_W1T   = OFF_XBF + (size_t)T_TOK * 1024 * 2;          // +32MB
    const size_t OFF_W2T   = OFF_W1T + (size_t)E_NUM * 1024 * 1024 * 2;   // +16MB
    const size_t OFF_H     = OFF_W2T + (size_t)E_NUM * 1024 * 1024 * 2;   // +16MB
    const size_t WS_NEED   = OFF_H + (size_t)(2 * T_TOK + 512) * 1024 * 2; // h + ragged pad

    if (ws_size < WS_NEED) {
        k_naive<<<T_TOK, 256, 0, stream>>>(x, Wr, br, W1, b1, W2, b2, out);
        return;
    }

    char* ws = (char*)d_ws;
    int*   cnt   = (int*)ws;
    int*   tok   = (int*)(ws + OFF_TOK);
    float* coef  = (float*)(ws + OFF_COEF);
    int*   tinfo = (int*)(ws + OFF_TINFO);
    float* c1arr = (float*)(ws + OFF_C1);
    u16*   xbf   = (u16*)(ws + OFF_XBF);
    u16*   w1t   = (u16*)(ws + OFF_W1T);
    u16*   w2t   = (u16*)(ws + OFF_W2T);
    u16*   hbuf  = (u16*)(ws + OFF_H);

    hipMemsetAsync(cnt, 0, 64, stream);
    hipMemsetAsync(d_out, 0, (size_t)out_size * sizeof(float), stream);
    k_transpose<<<dim3(32, 32, 8), 256, 0, stream>>>(W1, w1t);
    k_transpose<<<dim3(32, 32, 8), 256, 0, stream>>>(W2, w2t);
    k_router<<<4096, 256, 0, stream>>>(x, Wr, br, tinfo, c1arr, xbf);
    k_scatter<<<16, 1024, 0, stream>>>(tinfo, c1arr, cnt, tok, coef);
    dim3 gg(272, 16);
    k_gemm<0><<<gg, 256, 0, stream>>>(cnt, tok, coef, xbf, w1t, w2t, b1, b2, hbuf, out);
    k_gemm<1><<<gg, 256, 0, stream>>>(cnt, tok, coef, xbf, w1t, w2t, b1, b2, hbuf, out);
}

// Round 6
// 376.414 us; speedup vs baseline: 1.3112x; 1.0444x over previous
//
#include <hip/hip_runtime.h>
#include <cstdint>

typedef unsigned short u16;
using bf16x8 = __attribute__((ext_vector_type(8))) __bf16;
using f32x4  = __attribute__((ext_vector_type(4))) float;

#define T_TOK 16384   // B * N_OBJ
#define E_NUM 8

__device__ __forceinline__ u16 f2bf(float f) {
    union { float f; unsigned u; } v; v.f = f;
    unsigned r = (v.u + 0x7FFFu + ((v.u >> 16) & 1u)) >> 16;
    return (u16)r;
}

__device__ __forceinline__ void gload_lds16(const void* g, void* l) {
    __builtin_amdgcn_global_load_lds(
        (const __attribute__((address_space(1))) void*)g,
        (__attribute__((address_space(3))) void*)l, 16, 0, 0);
}

// ---------------- prep: W (E,1024,1024) f32 -> WT (E,1024,1024) bf16 transposed ----------------
__global__ __launch_bounds__(256) void k_transpose(const float* __restrict__ W, u16* __restrict__ WT) {
    __shared__ float tile[32][33];
    int e = blockIdx.z;
    int d0 = blockIdx.x << 5, h0 = blockIdx.y << 5;
    int tx = threadIdx.x & 31, ty = threadIdx.x >> 5;   // 32x8
    const size_t eo = (size_t)e << 20;
#pragma unroll
    for (int i = 0; i < 4; ++i) {
        int r = ty + i * 8;
        tile[r][tx] = W[eo + (size_t)(d0 + r) * 1024 + h0 + tx];
    }
    __syncthreads();
#pragma unroll
    for (int i = 0; i < 4; ++i) {
        int r = ty + i * 8;
        WT[eo + (size_t)(h0 + r) * 1024 + d0 + tx] = f2bf(tile[tx][r]);
    }
}

// ---------------- router: exact fp32 logits, top-2; writes per-token info; folds x->bf16 ----------------
__global__ __launch_bounds__(256) void k_router(const float* __restrict__ x, const float* __restrict__ Wr,
                                                const float* __restrict__ br,
                                                int* __restrict__ tinfo, float* __restrict__ c1arr,
                                                u16* __restrict__ xbf) {
    const int wave = threadIdx.x >> 6, lane = threadIdx.x & 63;
    const int t = (blockIdx.x << 2) + wave;
    const float* xr = x + (size_t)t * 1024;
    u16* xbr = xbf + (size_t)t * 1024;
    float acc[8] = {0, 0, 0, 0, 0, 0, 0, 0};
#pragma unroll
    for (int i = 0; i < 16; ++i) {
        int d = (i << 6) + lane;
        float xv = xr[d];
        xbr[d] = f2bf(xv);
        float4 w0 = *(const float4*)(Wr + d * 8);
        float4 w1 = *(const float4*)(Wr + d * 8 + 4);
        acc[0] += xv * w0.x; acc[1] += xv * w0.y; acc[2] += xv * w0.z; acc[3] += xv * w0.w;
        acc[4] += xv * w1.x; acc[5] += xv * w1.y; acc[6] += xv * w1.z; acc[7] += xv * w1.w;
    }
#pragma unroll
    for (int off = 32; off > 0; off >>= 1)
#pragma unroll
        for (int e = 0; e < 8; ++e) acc[e] += __shfl_xor(acc[e], off);

    if (lane == 0) {
        float v1 = -1e30f, v2 = -1e30f; int i1 = 0, i2 = 0;
#pragma unroll
        for (int e = 0; e < 8; ++e) {
            float v = acc[e] + br[e];
            if (v > v1) { v2 = v1; i2 = i1; v1 = v; i1 = e; }
            else if (v > v2) { v2 = v; i2 = e; }
        }
        float c1 = 1.f / (1.f + expf(v2 - v1));
        tinfo[t] = i1 | (i2 << 4);
        c1arr[t] = c1;
    }
}

// ---------------- scatter: LDS histogram -> per-block base -> 8 per-expert lists ----------------
__global__ __launch_bounds__(1024) void k_scatter(const int* __restrict__ tinfo, const float* __restrict__ c1arr,
                                                  int* __restrict__ cnt, int* __restrict__ tok,
                                                  float* __restrict__ coef) {
    __shared__ int lcnt[8];
    __shared__ int lbase[8];
    const int tid = threadIdx.x;
    const int t = blockIdx.x * 1024 + tid;
    if (tid < 8) lcnt[tid] = 0;
    __syncthreads();
    int info = tinfo[t];
    float c1 = c1arr[t];
    int g1 = info & 15;
    int g2 = (info >> 4) & 15;
    int o1 = atomicAdd(&lcnt[g1], 1);
    int o2 = atomicAdd(&lcnt[g2], 1);
    __syncthreads();
    if (tid < 8) lbase[tid] = atomicAdd(cnt + tid, lcnt[tid]);
    __syncthreads();
    int p1 = lbase[g1] + o1;
    tok[(g1 << 14) + p1] = t; coef[(g1 << 14) + p1] = c1;
    int p2 = lbase[g2] + o2;
    tok[(g2 << 14) + p2] = t; coef[(g2 << 14) + p2] = 1.f - c1;
}

// ---------------- grouped GEMM: R5's counted-vmcnt pipeline AT 4 blocks/CU ----------------
// 128x64 tile, BK=64. A double-buffered (a0/a1, 2x16KB, covers HBM/L3 gather latency
// one tile ahead); B SINGLE-buffered (8KB, L2-hot weight panel; restaged right after
// the release barrier, its L2 latency is covered by 16 waves/CU of TLP). Zero aux LDS
// (tok/coef/cnt read directly from global) -> LDS exactly 40960 B -> 4 blocks/CU.
// Per K-step: COMPUTE(t) -> lgkmcnt(0)+release-BAR -> STAGE_B(t+1)+STAGE_A(other,t+2)
// -> vmcnt(4) [drains A(t+1)+B(t+1), leaves A(t+2) in flight; NEVER 0 in loop] ->
// arrival-BAR. Peeled tail keeps all vmcnt literals.
// PHASE 0: h = relu(gather(xbf) @ W1T + b1) -> hbuf (bf16)
// PHASE 1: out[tok] += coef * (hbuf @ W2T + b2)   (atomicAdd, out pre-zeroed)
template <int PHASE>
__global__ __launch_bounds__(256, 4) void k_gemm(
    const int* __restrict__ cnt, const int* __restrict__ tok, const float* __restrict__ coef,
    const u16* __restrict__ xbf, const u16* __restrict__ w1t, const u16* __restrict__ w2t,
    const float* __restrict__ b1, const float* __restrict__ b2,
    u16* __restrict__ hbuf, float* __restrict__ out)
{
    __shared__ u16 a0_s[128 * 64];   // 16 KB
    __shared__ u16 a1_s[128 * 64];   // 16 KB
    __shared__ u16 b_s[64 * 64];     //  8 KB   -> total exactly 40 KB
    const int tid = threadIdx.x;

    // XCD-aware remap (bijective: 4352 = 8*544)
    int bid = blockIdx.x + blockIdx.y * 272;            // hw flat id, 4352 total
    int lin = (bid & 7) * 544 + (bid >> 3);
    int xt = lin >> 4, yt = lin & 15;

    // uniform scan over global cnt[] (L2-hot, 8 values): which (group, tile)?
    int g = -1, tile = 0, r0 = 0, mt = xt, rb = 0;
#pragma unroll
    for (int gg = 0; gg < 8; ++gg) {
        int c = cnt[gg], tg = (c + 127) >> 7;
        if (g < 0) {
            if (mt < tg) { g = gg; tile = mt; r0 = rb + (mt << 7); }
            else mt -= tg;
        }
        rb += c;
    }
    if (g < 0) return;
    const int cntg = cnt[g];
    const int e = g;
    const int nb = yt << 6;
    const int rowlim = cntg - (tile << 7);
    const int gbase = (g << 14) + (tile << 7);

    const int w = tid >> 6, l = tid & 63;
    const int wrow = (w >> 1) << 6, wcol = (w & 1) << 5;
    const u16* asrc = (PHASE == 0) ? xbf : hbuf;
    const u16* bsrc = (PHASE == 0) ? w1t : w2t;
    const size_t brow0 = ((size_t)e << 10) + nb;

    // T2 swizzle: LDS stays linear for global_load_lds; global SOURCE column is
    // pre-XORed so a swizzled ds_read returns the unswizzled element.
    const int sw = ((l & 7) ^ (l >> 3)) << 3;   // staging source col offset (elements)
    const int xk = (l & 7) << 3;                // read col XOR key (frag row&7 == l&7)

    // staging ptrs: A = 4 slots x 32 rows (per buffer), B = 2 slots x 32 rows
    const u16* aptr[4]; int ldsa[4];
#pragma unroll
    for (int j = 0; j < 4; ++j) {
        int row = (j << 5) + (w << 3) + (l >> 3);
        int arow;
        if (PHASE == 0) {
            int idx = gbase + row;
            arow = (row < rowlim) ? tok[idx] : 0;
        } else {
            arow = r0 + row;
        }
        aptr[j] = asrc + ((size_t)arow << 10) + sw;
        ldsa[j] = ((j << 5) + (w << 3)) * 64;
    }
    const u16* bptr[2]; int ldsb[2];
#pragma unroll
    for (int j = 0; j < 2; ++j) {
        int brow = (j << 5) + (w << 3) + (l >> 3);
        bptr[j] = bsrc + (brow0 + brow) * 1024 + sw;
        ldsb[j] = ((j << 5) + (w << 3)) * 64;
    }

    f32x4 acc[4][2];
#pragma unroll
    for (int mi = 0; mi < 4; ++mi)
#pragma unroll
        for (int ni = 0; ni < 2; ++ni) { acc[mi][ni][0] = 0.f; acc[mi][ni][1] = 0.f; acc[mi][ni][2] = 0.f; acc[mi][ni][3] = 0.f; }

#define STAGE_A(AS, KO)                                                        \
    {                                                                          \
        _Pragma("unroll")                                                      \
        for (int j = 0; j < 4; ++j) gload_lds16(aptr[j] + (KO), &AS[ldsa[j]]); \
    }
#define STAGE_B(KO)                                                            \
    {                                                                          \
        _Pragma("unroll")                                                      \
        for (int j = 0; j < 2; ++j) gload_lds16(bptr[j] + (KO), &b_s[ldsb[j]]); \
    }

#define COMPUTE(AS)                                                            \
    {                                                                          \
        _Pragma("unroll")                                                      \
        for (int ks = 0; ks < 64; ks += 32) {                                  \
            const int co = (ks + ((l >> 4) << 3)) ^ xk;                        \
            bf16x8 af[4], bfr[2];                                              \
            _Pragma("unroll")                                                  \
            for (int mi = 0; mi < 4; ++mi)                                     \
                af[mi] = *(const bf16x8*)&AS[(wrow + (mi << 4) + (l & 15)) * 64 + co]; \
            _Pragma("unroll")                                                  \
            for (int ni = 0; ni < 2; ++ni)                                     \
                bfr[ni] = *(const bf16x8*)&b_s[(wcol + (ni << 4) + (l & 15)) * 64 + co]; \
            _Pragma("unroll")                                                  \
            for (int mi = 0; mi < 4; ++mi)                                     \
                _Pragma("unroll")                                              \
                for (int ni = 0; ni < 2; ++ni)                                 \
                    acc[mi][ni] = __builtin_amdgcn_mfma_f32_16x16x32_bf16(af[mi], bfr[ni], acc[mi][ni], 0, 0, 0); \
        }                                                                      \
    }

#define VM4  asm volatile("s_waitcnt vmcnt(4)" ::: "memory")
#define VM0  asm volatile("s_waitcnt vmcnt(0)" ::: "memory")
#define LGK0 asm volatile("s_waitcnt lgkmcnt(0)" ::: "memory")
#define BAR() { asm volatile("" ::: "memory"); __builtin_amdgcn_s_barrier(); asm volatile("" ::: "memory"); }

    // prologue: A(t0), B(t0), A(t1). tok-dependency drained by compiler before staging.
    STAGE_A(a0_s, 0);
    STAGE_B(0);
    STAGE_A(a1_s, 64);
    VM4; BAR();                               // A(t0)+B(t0) landed; A(t1) in flight

    for (int kc = 0; kc < 14; kc += 2) {
        COMPUTE(a0_s);                        // tile kc
        LGK0; BAR();                          // all reads of a0+b done
        STAGE_B((kc + 1) << 6);
        STAGE_A(a0_s, (kc + 2) << 6);         // outstanding 10
        VM4; BAR();                           // A(kc+1)+B(kc+1) landed
        COMPUTE(a1_s);                        // tile kc+1
        LGK0; BAR();
        STAGE_B((kc + 2) << 6);
        STAGE_A(a1_s, (kc + 3) << 6);         // outstanding 10
        VM4; BAR();                           // A(kc+2)+B(kc+2) landed
    }
    // tail: a0 = t14 landed, a1 = A(t15) in flight, b = t14 landed
    COMPUTE(a0_s);                            // tile 14
    LGK0; BAR();
    STAGE_B(15 << 6);                         // outstanding 6
    VM0; BAR();                               // everything landed
    COMPUTE(a1_s);                            // tile 15

#undef STAGE_A
#undef STAGE_B
#undef COMPUTE
#undef VM4
#undef VM0
#undef LGK0
#undef BAR

    const int rq = (l >> 4) << 2;
    const int cl = l & 15;
#pragma unroll
    for (int ni = 0; ni < 2; ++ni) {
        int ccol = wcol + (ni << 4) + cl;
        float bias = (PHASE == 0 ? b1 : b2)[((size_t)e << 10) + nb + ccol];
#pragma unroll
        for (int mi = 0; mi < 4; ++mi) {
            int rbase = wrow + (mi << 4) + rq;
#pragma unroll
            for (int j = 0; j < 4; ++j) {
                int r = rbase + j;
                if (r < rowlim) {
                    float v = acc[mi][ni][j] + bias;
                    if constexpr (PHASE == 0) {
                        v = fmaxf(v, 0.f);
                        hbuf[(size_t)(r0 + r) * 1024 + nb + ccol] = f2bf(v);
                    } else {
                        int gi = gbase + r;
                        atomicAdd(out + ((size_t)tok[gi] << 10) + nb + ccol, v * coef[gi]);
                    }
                }
            }
        }
    }
}

// ---------------- insurance fallback (ws too small): slow but correct ----------------
__global__ __launch_bounds__(256) void k_naive(const float* __restrict__ x, const float* __restrict__ Wr,
    const float* __restrict__ br, const float* __restrict__ W1, const float* __restrict__ b1,
    const float* __restrict__ W2, const float* __restrict__ b2, float* __restrict__ out)
{
    __shared__ float xs[1024];
    __shared__ float hs[1024];
    __shared__ float red[4];
    __shared__ float lg[8];
    const int tid = threadIdx.x;
    const size_t t = blockIdx.x;
    for (int i = tid; i < 1024; i += 256) xs[i] = x[t * 1024 + i];
    __syncthreads();
    float lacc[8] = {0, 0, 0, 0, 0, 0, 0, 0};
    for (int d = tid; d < 1024; d += 256) {
        float xv = xs[d];
#pragma unroll
        for (int e = 0; e < 8; ++e) lacc[e] += xv * Wr[d * 8 + e];
    }
    for (int e = 0; e < 8; ++e) {
        float v = lacc[e];
        for (int off = 32; off > 0; off >>= 1) v += __shfl_xor(v, off);
        if ((tid & 63) == 0) red[tid >> 6] = v;
        __syncthreads();
        if (tid == 0) lg[e] = red[0] + red[1] + red[2] + red[3] + br[e];
        __syncthreads();
    }
    float v1 = -1e30f, v2 = -1e30f; int i1 = 0, i2 = 0;
    for (int e = 0; e < 8; ++e) {
        float v = lg[e];
        if (v > v1) { v2 = v1; i2 = i1; v1 = v; i1 = e; }
        else if (v > v2) { v2 = v; i2 = e; }
    }
    float c1 = 1.f / (1.f + expf(v2 - v1)), c2 = 1.f - c1;
    float yacc[4] = {0, 0, 0, 0};
    for (int slot = 0; slot < 2; ++slot) {
        int e = slot ? i2 : i1;
        float cw = slot ? c2 : c1;
        __syncthreads();
        float ha[4];
        for (int jb = 0; jb < 4; ++jb) {
            int j = (jb << 8) + tid;
            float a = b1[(e << 10) + j];
            for (int d = 0; d < 1024; ++d) a += xs[d] * W1[(((size_t)e << 10) + d) * 1024 + j];
            ha[jb] = fmaxf(a, 0.f);
        }
        for (int jb = 0; jb < 4; ++jb) hs[(jb << 8) + tid] = ha[jb];
        __syncthreads();
        for (int ob = 0; ob < 4; ++ob) {
            int o = (ob << 8) + tid;
            float a = b2[(e << 10) + o];
            for (int h = 0; h < 1024; ++h) a += hs[h] * W2[(((size_t)e << 10) + h) * 1024 + o];
            yacc[ob] += cw * a;
        }
    }
    for (int ob = 0; ob < 4; ++ob) out[t * 1024 + (ob << 8) + tid] = yacc[ob];
}

extern "C" void kernel_launch(void* const* d_in, const int* in_sizes, int n_in,
                              void* d_out, int out_size, void* d_ws, size_t ws_size,
                              hipStream_t stream) {
    const float* x  = (const float*)d_in[0];
    const float* Wr = (const float*)d_in[1];
    const float* br = (const float*)d_in[2];
    const float* W1 = (const float*)d_in[3];
    const float* b1 = (const float*)d_in[4];
    const float* W2 = (const float*)d_in[5];
    const float* b2 = (const float*)d_in[6];
    float* out = (float*)d_out;

    const size_t OFF_TOK   = (size_t)1 << 20;
    const size_t OFF_COEF  = (size_t)2 << 20;
    const size_t OFF_TINFO = (size_t)3 << 20;
    const size_t OFF_C1    = OFF_TINFO + (size_t)T_TOK * 4;
    const size_t OFF_XBF   = (size_t)4 << 20;
    const size_t OFF_W1T   = OFF_XBF + (size_t)T_TOK * 1024 * 2;          // +32MB
    const size_t OFF_W2T   = OFF_W1T + (size_t)E_NUM * 1024 * 1024 * 2;   // +16MB
    const size_t OFF_H     = OFF_W2T + (size_t)E_NUM * 1024 * 1024 * 2;   // +16MB
    const size_t WS_NEED   = OFF_H + (size_t)(2 * T_TOK + 512) * 1024 * 2; // h + ragged pad

    if (ws_size < WS_NEED) {
        k_naive<<<T_TOK, 256, 0, stream>>>(x, Wr, br, W1, b1, W2, b2, out);
        return;
    }

    char* ws = (char*)d_ws;
    int*   cnt   = (int*)ws;
    int*   tok   = (int*)(ws + OFF_TOK);
    float* coef  = (float*)(ws + OFF_COEF);
    int*   tinfo = (int*)(ws + OFF_TINFO);
    float* c1arr = (float*)(ws + OFF_C1);
    u16*   xbf   = (u16*)(ws + OFF_XBF);
    u16*   w1t   = (u16*)(ws + OFF_W1T);
    u16*   w2t   = (u16*)(ws + OFF_W2T);
    u16*   hbuf  = (u16*)(ws + OFF_H);

    hipMemsetAsync(cnt, 0, 64, stream);
    hipMemsetAsync(d_out, 0, (size_t)out_size * sizeof(float), stream);
    k_transpose<<<dim3(32, 32, 8), 256, 0, stream>>>(W1, w1t);
    k_transpose<<<dim3(32, 32, 8), 256, 0, stream>>>(W2, w2t);
    k_router<<<4096, 256, 0, stream>>>(x, Wr, br, tinfo, c1arr, xbf);
    k_scatter<<<16, 1024, 0, stream>>>(tinfo, c1arr, cnt, tok, coef);
    dim3 gg(272, 16);
    k_gemm<0><<<gg, 256, 0, stream>>>(cnt, tok, coef, xbf, w1t, w2t, b1, b2, hbuf, out);
    k_gemm<1><<<gg, 256, 0, stream>>>(cnt, tok, coef, xbf, w1t, w2t, b1, b2, hbuf, out);
}